// Round 3
// baseline (362.909 us; speedup 1.0000x reference)
//
#include <hip/hip_runtime.h>
#include <hip/hip_cooperative_groups.h>
#include <math.h>

// Problem constants: V=50257, H=2048, E=1024, L=4
#define LSTM_H 2048
#define LSTM_E 1024
#define LSTM_L 4

namespace cg = cooperative_groups;

__device__ __forceinline__ float sigmoidf_(float x) {
    return 1.0f / (1.0f + __expf(-x));
}

__device__ __forceinline__ float wave_reduce(float s) {
    #pragma unroll
    for (int off = 32; off > 0; off >>= 1)
        s += __shfl_down(s, off, 64);
    return s;
}

__device__ __forceinline__ float dot2048(const float* __restrict__ w,
                                         const float* __restrict__ v, int lane) {
    const float4* __restrict__ w4 = (const float4*)w;
    const float4* __restrict__ v4 = (const float4*)v;
    float s = 0.0f;
    #pragma unroll
    for (int t = 0; t < 8; ++t) {
        const int idx = lane + t * 64;
        float4 a = w4[idx];
        float4 b = v4[idx];
        s += a.x * b.x + a.y * b.y + a.z * b.z + a.w * b.w;
    }
    return s;
}

__device__ __forceinline__ float dot1024(const float* __restrict__ w,
                                         const float* __restrict__ v, int lane) {
    const float4* __restrict__ w4 = (const float4*)w;
    const float4* __restrict__ v4 = (const float4*)v;
    float s = 0.0f;
    #pragma unroll
    for (int t = 0; t < 4; ++t) {
        const int idx = lane + t * 64;
        float4 a = w4[idx];
        float4 b = v4[idx];
        s += a.x * b.x + a.y * b.y + a.z * b.z + a.w * b.w;
    }
    return s;
}

// ---------------- Fused cooperative kernel (grid-size agnostic) ----------------
// Stage A: layer-0 full gates + cell update; W_hh partials for layers 1..3.
// grid.sync(); Stage B_l (l=1..3): W_ihR part + partial -> cell update; sync.
// Stage FC.
__global__ __launch_bounds__(256, 4)
void lstm_fused_kernel(const int*   __restrict__ token,
                       const float* __restrict__ hidden,  // [L,1,H]
                       const float* __restrict__ cell,    // [L,1,H]
                       const float* __restrict__ emb,     // [V,E]
                       const float* __restrict__ W_ih0,   // [4H,E]
                       const float* __restrict__ W_ihR,   // [L-1,4H,H]
                       const float* __restrict__ W_hh,    // [L,4H,H]
                       const float* __restrict__ b_ih,    // [L,4H]
                       const float* __restrict__ b_hh,    // [L,4H]
                       const float* __restrict__ fc_W,    // [E,H]
                       const float* __restrict__ fc_b,    // [E]
                       float*       __restrict__ out,     // [E + L*H + L*H]
                       float*       __restrict__ part)    // ws: [3][4H]
{
    cg::grid_group grid = cg::this_grid();

    const int G    = gridDim.x;
    const int b    = blockIdx.x;
    const int wave = threadIdx.x >> 6;   // gate 0..3 (i,f,g,o)
    const int lane = threadIdx.x & 63;

    float* decoded = out;                             // [E]
    float* h_new   = out + LSTM_E;                    // [L*H]
    float* c_new   = out + LSTM_E + LSTM_L * LSTM_H;  // [L*H]

    __shared__ float gsh[4];

    const float* xemb = emb + (size_t)(*token) * LSTM_E;

    // ---- Stage A1: layer 0 full (so h_new[0..H) ready at first sync) ----
    for (int j = b; j < LSTM_H; j += G) {
        const int row = wave * LSTM_H + j;
        float s = dot1024(W_ih0 + (size_t)row * LSTM_E, xemb, lane)
                + dot2048(W_hh  + (size_t)row * LSTM_H, hidden, lane);
        s = wave_reduce(s);
        if (lane == 0) gsh[wave] = s + b_ih[row] + b_hh[row];
        __syncthreads();
        if (threadIdx.x == 0) {
            const float i_ = sigmoidf_(gsh[0]);
            const float f_ = sigmoidf_(gsh[1]);
            const float g_ = tanhf(gsh[2]);
            const float o_ = sigmoidf_(gsh[3]);
            const float c  = f_ * cell[j] + i_ * g_;
            c_new[j] = c;
            h_new[j] = o_ * tanhf(c);
        }
        __syncthreads();
    }

    // ---- Stage A2: W_hh partials for layers 1..3 (independent of h chain) ----
    #pragma unroll
    for (int l = 1; l < LSTM_L; ++l) {
        const float* hl = hidden + (size_t)l * LSTM_H;
        for (int j = b; j < LSTM_H; j += G) {
            const int row = wave * LSTM_H + j;
            const size_t w_off = (size_t)l * 4 * LSTM_H * LSTM_H + (size_t)row * LSTM_H;
            float s = dot2048(W_hh + w_off, hl, lane);
            s = wave_reduce(s);
            if (lane == 0)
                part[(size_t)(l - 1) * 4 * LSTM_H + row] =
                    s + b_ih[(size_t)l * 4 * LSTM_H + row]
                      + b_hh[(size_t)l * 4 * LSTM_H + row];
        }
    }

    grid.sync();

    // ---- Stages B1..B3 ----
    for (int l = 1; l < LSTM_L; ++l) {
        const float* hx = h_new + (size_t)(l - 1) * LSTM_H;
        for (int j = b; j < LSTM_H; j += G) {
            const int row = wave * LSTM_H + j;
            float s = dot2048(W_ihR + (size_t)(l - 1) * 4 * LSTM_H * LSTM_H
                                    + (size_t)row * LSTM_H, hx, lane);
            s = wave_reduce(s);
            if (lane == 0) gsh[wave] = s + part[(size_t)(l - 1) * 4 * LSTM_H + row];
            __syncthreads();
            if (threadIdx.x == 0) {
                const float i_ = sigmoidf_(gsh[0]);
                const float f_ = sigmoidf_(gsh[1]);
                const float g_ = tanhf(gsh[2]);
                const float o_ = sigmoidf_(gsh[3]);
                const float c  = f_ * cell[(size_t)l * LSTM_H + j] + i_ * g_;
                c_new[(size_t)l * LSTM_H + j] = c;
                h_new[(size_t)l * LSTM_H + j] = o_ * tanhf(c);
            }
            __syncthreads();
        }
        grid.sync();
    }

    // ---- Stage FC ----
    {
        const float* h3 = h_new + (size_t)(LSTM_L - 1) * LSTM_H;
        for (int r = b * 4 + wave; r < LSTM_E; r += G * 4) {
            float s = dot2048(fc_W + (size_t)r * LSTM_H, h3, lane);
            s = wave_reduce(s);
            if (lane == 0) decoded[r] = s + fc_b[r];
        }
    }
}

// ---------------- Fallback path: proven round-1 kernels ----------------
template<int INW>
__global__ __launch_bounds__(256)
void lstm_layer_kernel(const float* __restrict__ W_ih,
                       const float* __restrict__ W_hh,
                       const float* __restrict__ b_ih,
                       const float* __restrict__ b_hh,
                       const float* __restrict__ xbase,
                       const int*   __restrict__ token,
                       const float* __restrict__ h_in,
                       const float* __restrict__ c_in,
                       float* __restrict__ h_out,
                       float* __restrict__ c_out)
{
    const int j    = blockIdx.x;
    const int wave = threadIdx.x >> 6;
    const int lane = threadIdx.x & 63;

    const float* x = xbase;
    if (token) x += (size_t)(*token) * (size_t)INW;

    const int row = wave * LSTM_H + j;

    float s = 0.0f;
    if (INW == LSTM_E)
        s += dot1024(W_ih + (size_t)row * INW, x, lane);
    else
        s += dot2048(W_ih + (size_t)row * INW, x, lane);
    s += dot2048(W_hh + (size_t)row * LSTM_H, h_in, lane);
    s = wave_reduce(s);

    __shared__ float gsh[4];
    if (lane == 0) gsh[wave] = s + b_ih[row] + b_hh[row];
    __syncthreads();

    if (threadIdx.x == 0) {
        const float i_ = sigmoidf_(gsh[0]);
        const float f_ = sigmoidf_(gsh[1]);
        const float g_ = tanhf(gsh[2]);
        const float o_ = sigmoidf_(gsh[3]);
        const float c  = f_ * c_in[j] + i_ * g_;
        c_out[j] = c;
        h_out[j] = o_ * tanhf(c);
    }
}

__global__ __launch_bounds__(256)
void fc_kernel(const float* __restrict__ fc_W,
               const float* __restrict__ fc_b,
               const float* __restrict__ h,
               float* __restrict__ out)
{
    const int wave = threadIdx.x >> 6;
    const int lane = threadIdx.x & 63;
    const int r = blockIdx.x * 4 + wave;

    float s = dot2048(fc_W + (size_t)r * LSTM_H, h, lane);
    s = wave_reduce(s);
    if (lane == 0) out[r] = s + fc_b[r];
}

extern "C" void kernel_launch(void* const* d_in, const int* in_sizes, int n_in,
                              void* d_out, int out_size, void* d_ws, size_t ws_size,
                              hipStream_t stream) {
    const int*   token  = (const int*)d_in[0];
    const float* hidden = (const float*)d_in[1];
    const float* cell   = (const float*)d_in[2];
    const float* emb    = (const float*)d_in[3];
    const float* W_ih0  = (const float*)d_in[4];
    const float* W_ihR  = (const float*)d_in[5];
    const float* W_hh   = (const float*)d_in[6];
    const float* b_ih   = (const float*)d_in[7];
    const float* b_hh   = (const float*)d_in[8];
    const float* fc_W   = (const float*)d_in[9];
    const float* fc_b   = (const float*)d_in[10];

    float* out  = (float*)d_out;
    float* part = (float*)d_ws;   // 3 * 8192 floats = 96 KB

    void* args[] = {
        (void*)&token, (void*)&hidden, (void*)&cell, (void*)&emb,
        (void*)&W_ih0, (void*)&W_ihR, (void*)&W_hh, (void*)&b_ih,
        (void*)&b_hh, (void*)&fc_W, (void*)&fc_b, (void*)&out, (void*)&part
    };

    // Size the cooperative grid from the runtime's own occupancy numbers
    // (host-side queries; stream-independent -> graph-capture-safe).
    int dev = 0;
    (void)hipGetDevice(&dev);
    int numCU = 256;
    (void)hipDeviceGetAttribute(&numCU, hipDeviceAttributeMultiprocessorCount, dev);
    int maxB = 0;
    (void)hipOccupancyMaxActiveBlocksPerMultiprocessor(&maxB, lstm_fused_kernel, 256, 0);
    if (maxB < 1) maxB = 1;

    long cap = (long)numCU * (long)maxB;
    int tries[3];
    tries[0] = (int)(cap < 1024 ? cap : 1024);
    tries[1] = 512;
    tries[2] = 256;

    hipError_t e = hipErrorUnknown;
    int prev = 1 << 30;
    for (int t = 0; t < 3; ++t) {
        if (tries[t] >= prev || tries[t] < 1) continue;
        prev = tries[t];
        e = hipLaunchCooperativeKernel((void*)lstm_fused_kernel,
                                       dim3(tries[t]), dim3(256), args, 0, stream);
        if (e == hipSuccess) break;
        (void)hipGetLastError();  // clear sticky error
    }

    if (e != hipSuccess) {
        // Fallback: proven 5-kernel path (~107 us).
        float* decoded = out;
        float* h_new   = out + LSTM_E;
        float* c_new   = out + LSTM_E + LSTM_L * LSTM_H;
        const size_t WIH_STRIDE = (size_t)4 * LSTM_H * LSTM_H;
        const size_t B_STRIDE   = (size_t)4 * LSTM_H;

        lstm_layer_kernel<LSTM_E><<<LSTM_H, 256, 0, stream>>>(
            W_ih0, W_hh, b_ih, b_hh, emb, token, hidden, cell, h_new, c_new);

        for (int l = 1; l < LSTM_L; ++l) {
            lstm_layer_kernel<LSTM_H><<<LSTM_H, 256, 0, stream>>>(
                W_ihR + (size_t)(l - 1) * WIH_STRIDE,
                W_hh  + (size_t)l * WIH_STRIDE,
                b_ih  + (size_t)l * B_STRIDE,
                b_hh  + (size_t)l * B_STRIDE,
                h_new + (size_t)(l - 1) * LSTM_H, nullptr,
                hidden + (size_t)l * LSTM_H,
                cell   + (size_t)l * LSTM_H,
                h_new + (size_t)l * LSTM_H,
                c_new + (size_t)l * LSTM_H);
        }

        fc_kernel<<<LSTM_E / 4, 256, 0, stream>>>(
            fc_W, fc_b, h_new + (size_t)(LSTM_L - 1) * LSTM_H, decoded);
    }
}

// Round 4
// 128.166 us; speedup vs baseline: 2.8315x; 2.8315x over previous
//
#include <hip/hip_runtime.h>
#include <math.h>

// Problem constants: V=50257, H=2048, E=1024, L=4
#define LSTM_H 2048
#define LSTM_E 1024
#define LSTM_L 4

__device__ __forceinline__ float sigmoidf_(float x) {
    return 1.0f / (1.0f + __expf(-x));
}

__device__ __forceinline__ float wave_reduce(float s) {
    #pragma unroll
    for (int off = 32; off > 0; off >>= 1)
        s += __shfl_down(s, off, 64);
    return s;
}

__device__ __forceinline__ float dot2048(const float* __restrict__ w,
                                         const float* __restrict__ v, int lane) {
    const float4* __restrict__ w4 = (const float4*)w;
    const float4* __restrict__ v4 = (const float4*)v;
    float s = 0.0f;
    #pragma unroll
    for (int t = 0; t < 8; ++t) {
        const int idx = lane + t * 64;
        float4 a = w4[idx];
        float4 b = v4[idx];
        s += a.x * b.x + a.y * b.y + a.z * b.z + a.w * b.w;
    }
    return s;
}

// ---------------- K0: all dependency-free matvec work ----------------
// One block per hidden unit j (2048 blocks, 4 waves = gates i,f,g,o).
// Wave computes, for its gate row:
//   - layer 0 full: W_ih0[row] @ emb[tok] + W_hh[0][row] @ hidden[0]  -> gate
//   - layers 1..3:  W_hh[l][row] @ hidden[l] + biases                 -> part[l-1][row]
// Then thread 0 applies the layer-0 cell update.
// 8 independent weight streams per wave -> deep memory-level parallelism.
__global__ __launch_bounds__(256)
void k0_fused_partials(const int*   __restrict__ token,
                       const float* __restrict__ hidden,  // [L,1,H]
                       const float* __restrict__ cell,    // [L,1,H]
                       const float* __restrict__ emb,     // [V,E]
                       const float* __restrict__ W_ih0,   // [4H,E]
                       const float* __restrict__ W_hh,    // [L,4H,H]
                       const float* __restrict__ b_ih,    // [L,4H]
                       const float* __restrict__ b_hh,    // [L,4H]
                       float* __restrict__ h_new,         // [L*H]
                       float* __restrict__ c_new,         // [L*H]
                       float* __restrict__ part)          // [3][4H]
{
    const int j    = blockIdx.x;
    const int wave = threadIdx.x >> 6;   // gate 0..3
    const int lane = threadIdx.x & 63;
    const int row  = wave * LSTM_H + j;

    // Prefetch biases early (independent scalar loads).
    const float bias0 = b_ih[row] + b_hh[row];
    const float bias1 = b_ih[1 * 4 * LSTM_H + row] + b_hh[1 * 4 * LSTM_H + row];
    const float bias2 = b_ih[2 * 4 * LSTM_H + row] + b_hh[2 * 4 * LSTM_H + row];
    const float bias3 = b_ih[3 * 4 * LSTM_H + row] + b_hh[3 * 4 * LSTM_H + row];
    const float c_in0 = cell[j];

    const float4* __restrict__ x4  = (const float4*)(emb + (size_t)(*token) * LSTM_E);
    const float4* __restrict__ v0  = (const float4*)(hidden);
    const float4* __restrict__ v1  = (const float4*)(hidden + LSTM_H);
    const float4* __restrict__ v2  = (const float4*)(hidden + 2 * LSTM_H);
    const float4* __restrict__ v3  = (const float4*)(hidden + 3 * LSTM_H);

    const size_t LSTRIDE4 = (size_t)4 * LSTM_H * LSTM_H / 4;  // one layer of W_hh, in float4
    const float4* __restrict__ w0 = (const float4*)(W_hh) + (size_t)row * (LSTM_H / 4);
    const float4* __restrict__ w1 = w0 + LSTRIDE4;
    const float4* __restrict__ w2 = w1 + LSTRIDE4;
    const float4* __restrict__ w3 = w2 + LSTRIDE4;
    const float4* __restrict__ wi = (const float4*)(W_ih0) + (size_t)row * (LSTM_E / 4);

    float a0 = 0.f, a1 = 0.f, a2 = 0.f, a3 = 0.f, ax = 0.f;

    #pragma unroll
    for (int t = 0; t < 8; ++t) {
        const int idx = lane + t * 64;
        {
            float4 w = w0[idx], v = v0[idx];
            a0 += w.x * v.x + w.y * v.y + w.z * v.z + w.w * v.w;
        }
        {
            float4 w = w1[idx], v = v1[idx];
            a1 += w.x * v.x + w.y * v.y + w.z * v.z + w.w * v.w;
        }
        {
            float4 w = w2[idx], v = v2[idx];
            a2 += w.x * v.x + w.y * v.y + w.z * v.z + w.w * v.w;
        }
        {
            float4 w = w3[idx], v = v3[idx];
            a3 += w.x * v.x + w.y * v.y + w.z * v.z + w.w * v.w;
        }
        if (t < 4) {
            float4 w = wi[idx], v = x4[idx];
            ax += w.x * v.x + w.y * v.y + w.z * v.z + w.w * v.w;
        }
    }

    const float g0 = wave_reduce(ax + a0);
    const float p1 = wave_reduce(a1);
    const float p2 = wave_reduce(a2);
    const float p3 = wave_reduce(a3);

    __shared__ float gsh[4];
    if (lane == 0) {
        gsh[wave] = g0 + bias0;
        part[0 * 4 * LSTM_H + row] = p1 + bias1;
        part[1 * 4 * LSTM_H + row] = p2 + bias2;
        part[2 * 4 * LSTM_H + row] = p3 + bias3;
    }
    __syncthreads();

    if (threadIdx.x == 0) {
        const float i_ = sigmoidf_(gsh[0]);
        const float f_ = sigmoidf_(gsh[1]);
        const float g_ = tanhf(gsh[2]);
        const float o_ = sigmoidf_(gsh[3]);
        const float c  = f_ * c_in0 + i_ * g_;
        c_new[j] = c;
        h_new[j] = o_ * tanhf(c);
    }
}

// ---------------- KB: sequential part of layer l (l = 1..3) ----------------
// gates = W_ihR[l-1] @ h_{l-1} + part[l-1]  -> cell update.
__global__ __launch_bounds__(256)
void kb_layer(const float* __restrict__ W_ih,   // [4H, H] (layer's W_ihR slice)
              const float* __restrict__ part_l, // [4H] precomputed W_hh part + biases
              const float* __restrict__ hx,     // [H] h_{l-1}
              const float* __restrict__ c_in,   // [H] input cell for this layer
              float* __restrict__ h_out,        // [H]
              float* __restrict__ c_out)        // [H]
{
    const int j    = blockIdx.x;
    const int wave = threadIdx.x >> 6;
    const int lane = threadIdx.x & 63;
    const int row  = wave * LSTM_H + j;

    const float p    = part_l[row];   // prefetch: independent of the dot
    const float c_in_j = c_in[j];

    float s = dot2048(W_ih + (size_t)row * LSTM_H, hx, lane);
    s = wave_reduce(s);

    __shared__ float gsh[4];
    if (lane == 0) gsh[wave] = s + p;
    __syncthreads();

    if (threadIdx.x == 0) {
        const float i_ = sigmoidf_(gsh[0]);
        const float f_ = sigmoidf_(gsh[1]);
        const float g_ = tanhf(gsh[2]);
        const float o_ = sigmoidf_(gsh[3]);
        const float c  = f_ * c_in_j + i_ * g_;
        c_out[j] = c;
        h_out[j] = o_ * tanhf(c);
    }
}

// ---------------- FC: decoded = fc_W @ h3 + fc_b ----------------
__global__ __launch_bounds__(256)
void kfc(const float* __restrict__ fc_W,   // [E, H]
         const float* __restrict__ fc_b,   // [E]
         const float* __restrict__ h,      // [H]
         float* __restrict__ out)          // [E]
{
    const int wave = threadIdx.x >> 6;
    const int lane = threadIdx.x & 63;
    const int r = blockIdx.x * 4 + wave;

    const float b = fc_b[r];
    float s = dot2048(fc_W + (size_t)r * LSTM_H, h, lane);
    s = wave_reduce(s);
    if (lane == 0) out[r] = s + b;
}

extern "C" void kernel_launch(void* const* d_in, const int* in_sizes, int n_in,
                              void* d_out, int out_size, void* d_ws, size_t ws_size,
                              hipStream_t stream) {
    const int*   token  = (const int*)d_in[0];
    const float* hidden = (const float*)d_in[1];
    const float* cell   = (const float*)d_in[2];
    const float* emb    = (const float*)d_in[3];
    const float* W_ih0  = (const float*)d_in[4];
    const float* W_ihR  = (const float*)d_in[5];
    const float* W_hh   = (const float*)d_in[6];
    const float* b_ih   = (const float*)d_in[7];
    const float* b_hh   = (const float*)d_in[8];
    const float* fc_W   = (const float*)d_in[9];
    const float* fc_b   = (const float*)d_in[10];

    float* out     = (float*)d_out;
    float* decoded = out;                              // [E]
    float* h_new   = out + LSTM_E;                     // [L*H]
    float* c_new   = out + LSTM_E + LSTM_L * LSTM_H;   // [L*H]
    float* part    = (float*)d_ws;                     // [3][4H] = 96 KB

    const size_t WIH_STRIDE = (size_t)4 * LSTM_H * LSTM_H;
    const size_t P_STRIDE   = (size_t)4 * LSTM_H;

    // K0: layer-0 full + all W_hh partials (301 MB, fully parallel).
    k0_fused_partials<<<LSTM_H, 256, 0, stream>>>(
        token, hidden, cell, emb, W_ih0, W_hh, b_ih, b_hh,
        h_new, c_new, part);

    // Sequential chain: layers 1..3 (67 MB each).
    for (int l = 1; l < LSTM_L; ++l) {
        kb_layer<<<LSTM_H, 256, 0, stream>>>(
            W_ihR + (size_t)(l - 1) * WIH_STRIDE,
            part  + (size_t)(l - 1) * P_STRIDE,
            h_new + (size_t)(l - 1) * LSTM_H,
            cell  + (size_t)l * LSTM_H,
            h_new + (size_t)l * LSTM_H,
            c_new + (size_t)l * LSTM_H);
    }

    // FC (8.4 MB).
    kfc<<<LSTM_E / 4, 256, 0, stream>>>(
        fc_W, fc_b, h_new + (size_t)(LSTM_L - 1) * LSTM_H, decoded);
}

// Round 5
// 99.919 us; speedup vs baseline: 3.6320x; 1.2827x over previous
//
#include <hip/hip_runtime.h>
#include <math.h>

// Problem constants: V=50257, H=2048, E=1024, L=4
#define LSTM_H 2048
#define LSTM_E 1024
#define LSTM_L 4

__device__ __forceinline__ float sigmoidf_(float x) {
    return 1.0f / (1.0f + __expf(-x));
}

__device__ __forceinline__ float wave_reduce(float s) {
    #pragma unroll
    for (int off = 32; off > 0; off >>= 1)
        s += __shfl_down(s, off, 64);
    return s;
}

__device__ __forceinline__ float dot2048(const float* __restrict__ w,
                                         const float* __restrict__ v, int lane) {
    const float4* __restrict__ w4 = (const float4*)w;
    const float4* __restrict__ v4 = (const float4*)v;
    float s = 0.0f;
    #pragma unroll
    for (int t = 0; t < 8; ++t) {
        const int idx = lane + t * 64;
        float4 a = w4[idx];
        float4 b = v4[idx];
        s += a.x * b.x + a.y * b.y + a.z * b.z + a.w * b.w;
    }
    return s;
}

__device__ __forceinline__ float dot1024(const float* __restrict__ w,
                                         const float* __restrict__ v, int lane) {
    const float4* __restrict__ w4 = (const float4*)w;
    const float4* __restrict__ v4 = (const float4*)v;
    float s = 0.0f;
    #pragma unroll
    for (int t = 0; t < 4; ++t) {
        const int idx = lane + t * 64;
        float4 a = w4[idx];
        float4 b = v4[idx];
        s += a.x * b.x + a.y * b.y + a.z * b.z + a.w * b.w;
    }
    return s;
}

// ---------------- K1: all dependency-free work, <=2 streams per wave ----------
// Blocks [0, 2048): unit-mode — layer 0 full gates + cell update for unit j.
//   Wave = gate; 2 streams (W_ih0 row 4KB + W_hh0 row 8KB). Round-1-proven shape.
// Blocks [2048, 8192): row-mode — W_hh partials for layers 1..3.
//   Wave = one 8KB row (1 stream); block covers 4 CONSECUTIVE rows = 32KB
//   contiguous; layer boundaries align with blocks (8192 % 4 == 0).
__global__ __launch_bounds__(256)
void k1_parallel(const int*   __restrict__ token,
                 const float* __restrict__ hidden,  // [L,1,H]
                 const float* __restrict__ cell,    // [L,1,H]
                 const float* __restrict__ emb,     // [V,E]
                 const float* __restrict__ W_ih0,   // [4H,E]
                 const float* __restrict__ W_hh,    // [L,4H,H]
                 const float* __restrict__ b_ih,    // [L,4H]
                 const float* __restrict__ b_hh,    // [L,4H]
                 float* __restrict__ h_new,         // [L*H]
                 float* __restrict__ c_new,         // [L*H]
                 float* __restrict__ part)          // [3][4H]
{
    const int wave = threadIdx.x >> 6;
    const int lane = threadIdx.x & 63;

    if (blockIdx.x < LSTM_H) {
        // ---- unit-mode: layer 0, unit j ----
        const int j   = blockIdx.x;
        const int row = wave * LSTM_H + j;

        const float bias  = b_ih[row] + b_hh[row];
        const float c_in0 = cell[j];
        const float* xemb = emb + (size_t)(*token) * LSTM_E;

        float s = dot1024(W_ih0 + (size_t)row * LSTM_E, xemb, lane)
                + dot2048(W_hh  + (size_t)row * LSTM_H, hidden, lane);
        s = wave_reduce(s);

        __shared__ float gsh[4];
        if (lane == 0) gsh[wave] = s + bias;
        __syncthreads();

        if (threadIdx.x == 0) {
            const float i_ = sigmoidf_(gsh[0]);
            const float f_ = sigmoidf_(gsh[1]);
            const float g_ = tanhf(gsh[2]);
            const float o_ = sigmoidf_(gsh[3]);
            const float c  = f_ * c_in0 + i_ * g_;
            c_new[j] = c;
            h_new[j] = o_ * tanhf(c);
        }
    } else {
        // ---- row-mode: W_hh partial for layers 1..3 ----
        const int r     = (blockIdx.x - LSTM_H) * 4 + wave;  // 0 .. 24575
        const int lidx  = r >> 13;          // 0..2  -> layer lidx+1
        const int rowin = r & 8191;         // row within the layer's [4H]

        const size_t brow = (size_t)(lidx + 1) * 4 * LSTM_H + rowin;
        const float bias = b_ih[brow] + b_hh[brow];

        const float* w = W_hh + (size_t)(lidx + 1) * 4 * LSTM_H * LSTM_H
                               + (size_t)rowin * LSTM_H;
        const float* v = hidden + (size_t)(lidx + 1) * LSTM_H;

        float s = dot2048(w, v, lane);
        s = wave_reduce(s);
        if (lane == 0) part[r] = s + bias;
    }
}

// ---------------- KB: sequential part of layer l (l = 1..3) ----------------
// gates = W_ihR[l-1] @ h_{l-1} + part[l-1]  -> cell update.  1 stream/wave.
__global__ __launch_bounds__(256)
void kb_layer(const float* __restrict__ W_ih,   // [4H, H] (layer's W_ihR slice)
              const float* __restrict__ part_l, // [4H] W_hh part + biases
              const float* __restrict__ hx,     // [H] h_{l-1}
              const float* __restrict__ c_in,   // [H]
              float* __restrict__ h_out,        // [H]
              float* __restrict__ c_out)        // [H]
{
    const int j    = blockIdx.x;
    const int wave = threadIdx.x >> 6;
    const int lane = threadIdx.x & 63;
    const int row  = wave * LSTM_H + j;

    const float p      = part_l[row];
    const float c_in_j = c_in[j];

    float s = dot2048(W_ih + (size_t)row * LSTM_H, hx, lane);
    s = wave_reduce(s);

    __shared__ float gsh[4];
    if (lane == 0) gsh[wave] = s + p;
    __syncthreads();

    if (threadIdx.x == 0) {
        const float i_ = sigmoidf_(gsh[0]);
        const float f_ = sigmoidf_(gsh[1]);
        const float g_ = tanhf(gsh[2]);
        const float o_ = sigmoidf_(gsh[3]);
        const float c  = f_ * c_in_j + i_ * g_;
        c_out[j] = c;
        h_out[j] = o_ * tanhf(c);
    }
}

// ---------------- FC: decoded = fc_W @ h3 + fc_b ----------------
__global__ __launch_bounds__(256)
void kfc(const float* __restrict__ fc_W,   // [E, H]
         const float* __restrict__ fc_b,   // [E]
         const float* __restrict__ h,      // [H]
         float* __restrict__ out)          // [E]
{
    const int wave = threadIdx.x >> 6;
    const int lane = threadIdx.x & 63;
    const int r = blockIdx.x * 4 + wave;

    const float b = fc_b[r];
    float s = dot2048(fc_W + (size_t)r * LSTM_H, h, lane);
    s = wave_reduce(s);
    if (lane == 0) out[r] = s + b;
}

extern "C" void kernel_launch(void* const* d_in, const int* in_sizes, int n_in,
                              void* d_out, int out_size, void* d_ws, size_t ws_size,
                              hipStream_t stream) {
    const int*   token  = (const int*)d_in[0];
    const float* hidden = (const float*)d_in[1];
    const float* cell   = (const float*)d_in[2];
    const float* emb    = (const float*)d_in[3];
    const float* W_ih0  = (const float*)d_in[4];
    const float* W_ihR  = (const float*)d_in[5];
    const float* W_hh   = (const float*)d_in[6];
    const float* b_ih   = (const float*)d_in[7];
    const float* b_hh   = (const float*)d_in[8];
    const float* fc_W   = (const float*)d_in[9];
    const float* fc_b   = (const float*)d_in[10];

    float* out     = (float*)d_out;
    float* decoded = out;                              // [E]
    float* h_new   = out + LSTM_E;                     // [L*H]
    float* c_new   = out + LSTM_E + LSTM_L * LSTM_H;   // [L*H]
    float* part    = (float*)d_ws;                     // [3][4H] = 96 KB

    const size_t WIH_STRIDE = (size_t)4 * LSTM_H * LSTM_H;
    const size_t P_STRIDE   = (size_t)4 * LSTM_H;

    // K1: layer-0 full + all W_hh partials (301.5 MB), <=2 streams per wave.
    k1_parallel<<<8192, 256, 0, stream>>>(
        token, hidden, cell, emb, W_ih0, W_hh, b_ih, b_hh,
        h_new, c_new, part);

    // Sequential chain: layers 1..3 (67 MB each, 1 stream per wave).
    for (int l = 1; l < LSTM_L; ++l) {
        kb_layer<<<LSTM_H, 256, 0, stream>>>(
            W_ihR + (size_t)(l - 1) * WIH_STRIDE,
            part  + (size_t)(l - 1) * P_STRIDE,
            h_new + (size_t)(l - 1) * LSTM_H,
            cell  + (size_t)l * LSTM_H,
            h_new + (size_t)l * LSTM_H,
            c_new + (size_t)l * LSTM_H);
    }

    // FC (8.4 MB).
    kfc<<<LSTM_E / 4, 256, 0, stream>>>(
        fc_W, fc_b, h_new + (size_t)(LSTM_L - 1) * LSTM_H, decoded);
}